// Round 7
// baseline (63.412 us; speedup 1.0000x reference)
//
#include <hip/hip_runtime.h>

// SE(2) depthwise group conv via bf16 MFMA (fp32 accum), pipelined.
// Per (b,c): out[8t][16384 pix] = W[8 x 200] @ im2col(x)[200 x 16384]
//   K = 28 taps x 8 orientations (o innermost), taps 25-27 zero weights.
// mfma_f32_16x16x32_bf16, A = x-frag (rows = 16 pixels), B = w-frag (cols = t):
//   D lane l: col = l&15 (t, 8 real), row = (l>>4)*4+reg (pixel) -> float4 store.
// Block = (b,c, 16-row strip); iterates 4 x-tiles (32 cols each) with
// double-buffered LDS: load(next)->regs | compute(cur) | pack/write(next).
// LDS x-buf: [20 r][36 c][8 o] bf16 = 11520 B each; chunk (r,c) = 16 B.
// Grid 2048, XCD-chunked swizzle: each XCD owns whole (b,c) planes.

typedef short bf16x8 __attribute__((ext_vector_type(8)));
typedef float f32x4 __attribute__((ext_vector_type(4)));

#define NCH 720   // 20 rows x 36 cols chunks per tile

__device__ inline unsigned short f2bf(float f) {   // RNE f32->bf16
    unsigned int u = __float_as_uint(f);
    u += 0x7fffu + ((u >> 16) & 1u);
    return (unsigned short)(u >> 16);
}
__device__ inline unsigned pk2(float a, float b) {
    return (unsigned)f2bf(a) | ((unsigned)f2bf(b) << 16);
}

// cos/sin of 2*pi*t/8, f32. NN-rounding margins >=0.035 -> table-vs-libm safe.
__device__ __constant__ float CA8[8] = {1.0f, 0.70710678f, 0.0f, -0.70710678f,
                                        -1.0f, -0.70710678f, 0.0f, 0.70710678f};
__device__ __constant__ float SA8[8] = {0.0f, 0.70710678f, 1.0f, 0.70710678f,
                                        0.0f, -0.70710678f, -1.0f, -0.70710678f};

__global__ __launch_bounds__(256)
void se2_mfma(const float* __restrict__ x, const float* __restrict__ kern,
              float* __restrict__ out) {
    __shared__ __align__(16) unsigned short ldsx[2][NCH * 8];  // 2 x 11520 B
    __shared__ __align__(16) unsigned short ldsw[8 * 28 * 8];  // 3584 B

    // XCD-chunked bijective swizzle: 2048 blocks, 8 XCDs, 256 per XCD.
    const int bid = (blockIdx.x & 7) * 256 + (blockIdx.x >> 3);
    const int ys = bid & 7;           // 16-row strip
    const int bc = bid >> 3;          // b*32 + c
    const int c  = bc & 31;
    const int Y0 = ys * 16;
    const int tid = threadIdx.x;

    // ---- rotated weights -> ldsw[t][tap][o] bf16 (tap>=25 => 0) ----
    for (int e = tid; e < 1792; e += 256) {
        int t   = e / 224;
        int rem = e - t * 224;
        int tap = rem >> 3;
        int o   = rem & 7;
        float w = 0.0f;
        if (tap < 25) {
            int dy = tap / 5, dx = tap - 5 * (tap / 5);
            float ca = CA8[t], sa = SA8[t];
            float xx = (float)dx - 2.0f, yy = (float)dy - 2.0f;
            int iy = (int)rintf(sa * xx + ca * yy + 2.0f);  // RNE == jnp.round
            int ix = (int)rintf(ca * xx - sa * yy + 2.0f);
            if (iy >= 0 && iy < 5 && ix >= 0 && ix < 5) {
                int tp = (o - t) & 7;
                w = kern[(c * 8 + tp) * 25 + iy * 5 + ix];
            }
        }
        ldsw[e] = f2bf(w);
    }
    __syncthreads();   // ldsw written by all threads; wfrag below reads it

    const float* xbase = x + (size_t)bc * 131072;

    // chunk e -> (r = e/36, col = e%36); gy = Y0-2+r, gx = xt*32-2+col
    auto loadch = [&](int xt, int e, float (&v)[8]) {
        int r = e / 36, col = e - r * 36;
        int gy = Y0 - 2 + r, gx = xt * 32 - 2 + col;
        if (gy >= 0 && gy < 128 && gx >= 0 && gx < 128) {
            const float* src = xbase + gy * 128 + gx;
#pragma unroll
            for (int o = 0; o < 8; ++o) v[o] = src[o * 16384];
        } else {
#pragma unroll
            for (int o = 0; o < 8; ++o) v[o] = 0.0f;
        }
    };
    auto packch = [&](int buf, int e, const float (&v)[8]) {
        *reinterpret_cast<uint4*>(&ldsx[buf][e * 8]) =
            make_uint4(pk2(v[0], v[1]), pk2(v[2], v[3]),
                       pk2(v[4], v[5]), pk2(v[6], v[7]));
    };

    // ---- per-lane MFMA constants ----
    const int lane  = tid & 63;
    const int wv    = tid >> 6;        // wave: rows yl = wv*4 .. wv*4+3
    const int g     = lane >> 4;       // k-group
    const int col16 = lane & 15;

    bf16x8 wfrag[7];
    int    tapoff[7];
    const bf16x8 zfrag = {0, 0, 0, 0, 0, 0, 0, 0};
#pragma unroll
    for (int cc = 0; cc < 7; ++cc) {
        int tap  = cc * 4 + g;
        int tapc = tap < 25 ? tap : 24;
        int dy = tapc / 5, dx = tapc - 5 * (tapc / 5);
        tapoff[cc] = (dy * 36 + dx) * 8;          // in shorts
        wfrag[cc] = (col16 < 8)
            ? *reinterpret_cast<const bf16x8*>(&ldsw[(col16 * 28 + tap) * 8])
            : zfrag;
    }

    float* outl = out + (size_t)bc * 131072 + (size_t)col16 * 16384 + g * 4;

    // compute 4 col-tiles (half = 0: ct 0..3, half = 1: ct 4..7)
    auto compute = [&](int buf, int xt, int half) {
#pragma unroll
        for (int j = 0; j < 4; ++j) {
            int ct = half * 4 + j;
            int yl = wv * 4 + (ct >> 1);
            int xh = ct & 1;
            int baseS = (yl * 36 + xh * 16 + col16) * 8;
            const unsigned short* px = &ldsx[buf][0];
            f32x4 acc = {0.f, 0.f, 0.f, 0.f};
#pragma unroll
            for (int cc = 0; cc < 7; ++cc) {
                bf16x8 xf = *reinterpret_cast<const bf16x8*>(&px[baseS + tapoff[cc]]);
                acc = __builtin_amdgcn_mfma_f32_16x16x32_bf16(xf, wfrag[cc], acc, 0, 0, 0);
            }
            if (col16 < 8)
                *reinterpret_cast<float4*>(outl + (size_t)(Y0 + yl) * 128 +
                                           xt * 32 + xh * 16) =
                    make_float4(acc[0], acc[1], acc[2], acc[3]);
        }
    };

    float s0[8], s1[8], s2[8];
    const bool has2 = (tid < NCH - 512);   // 208 threads own a 3rd chunk

    // ---- prologue: stage tile 0 into buf 0 ----
    loadch(0, tid, s0);
    loadch(0, tid + 256, s1);
    if (has2) loadch(0, tid + 512, s2);
    packch(0, tid, s0);
    packch(0, tid + 256, s1);
    if (has2) packch(0, tid + 512, s2);
    __syncthreads();

    int cur = 0;
#pragma unroll 1
    for (int xt = 0; xt < 4; ++xt) {
        const bool pre = (xt < 3);
        if (pre) { loadch(xt + 1, tid, s0); loadch(xt + 1, tid + 256, s1); }
        compute(cur, xt, 0);
        if (pre) {
            packch(cur ^ 1, tid, s0);
            packch(cur ^ 1, tid + 256, s1);
            if (has2) loadch(xt + 1, tid + 512, s2);
        }
        compute(cur, xt, 1);
        if (pre && has2) packch(cur ^ 1, tid + 512, s2);
        __syncthreads();
        cur ^= 1;
    }
}

extern "C" void kernel_launch(void* const* d_in, const int* in_sizes, int n_in,
                              void* d_out, int out_size, void* d_ws, size_t ws_size,
                              hipStream_t stream) {
    const float* x    = (const float*)d_in[0];
    const float* kern = (const float*)d_in[1];
    float* out = (float*)d_out;
    dim3 grid(2048), block(256);   // 8b * 32c * 8 strips (swizzled in-kernel)
    se2_mfma<<<grid, block, 0, stream>>>(x, kern, out);
}

// Round 8
// 56.728 us; speedup vs baseline: 1.1178x; 1.1178x over previous
//
#include <hip/hip_runtime.h>

// SE(2) depthwise group conv via bf16 MFMA (fp32 accum).
// Per (b,c): out[8t][16384 pix] = W[8 x 200] @ im2col(x)[200 x 16384]
//   K = 28 taps x 8 orientations (o innermost), taps 25-27 zero weights.
// mfma_f32_16x16x32_bf16, A = x-frag (rows = 16 pixels), B = w-frag (cols = t):
//   A lane l: row = l&15 (pixel), k = 8*(l>>4)+j
//   B lane l: col = l&15 (t; 8 real + 8 zero), k = 8*(l>>4)+j
//   D lane l: col = l&15 (t), row = (l>>4)*4+reg (pixel) -> float4 store.
// LDS x-tile: [36 r][36 c][8 o] bf16; (r,c) chunk = 16 B; col 0 <-> gx = X0-2.
// Staging: 3 fixed rounds x 2 chunks/thread (loads batched -> 3 exposed
// latencies instead of 5-6). Compute: xh-pairs, unroll 2 -> 4 MFMA chains.
// Grid 4096, XCD-chunked swizzle: 16 tiles of one (b,c) share an XCD's L2.

typedef short bf16x8 __attribute__((ext_vector_type(8)));
typedef float f32x4 __attribute__((ext_vector_type(4)));

__device__ inline unsigned short f2bf(float f) {   // RNE f32->bf16
    unsigned int u = __float_as_uint(f);
    u += 0x7fffu + ((u >> 16) & 1u);
    return (unsigned short)(u >> 16);
}
__device__ inline unsigned pk2(float a, float b) {
    return (unsigned)f2bf(a) | ((unsigned)f2bf(b) << 16);
}

// cos/sin of 2*pi*t/8, f32. NN-rounding margins >=0.035 -> table-vs-libm safe.
__device__ __constant__ float CA8[8] = {1.0f, 0.70710678f, 0.0f, -0.70710678f,
                                        -1.0f, -0.70710678f, 0.0f, 0.70710678f};
__device__ __constant__ float SA8[8] = {0.0f, 0.70710678f, 1.0f, 0.70710678f,
                                        0.0f, -0.70710678f, -1.0f, -0.70710678f};

__global__ __launch_bounds__(256, 5)
void se2_mfma(const float* __restrict__ x, const float* __restrict__ kern,
              float* __restrict__ out) {
    __shared__ __align__(16) unsigned short ldsx[36 * 36 * 8];  // 20736 B
    __shared__ __align__(16) unsigned short ldsw[8 * 28 * 8];   //  3584 B

    // XCD-chunked bijective swizzle: 4096 blocks, 8 XCDs, 512 per XCD.
    const int bid = (blockIdx.x & 7) * 512 + (blockIdx.x >> 3);
    const int tx = bid & 3, ty = (bid >> 2) & 3;
    const int bc = bid >> 4;          // b*32 + c
    const int c  = bc & 31;
    const int X0 = tx * 32, Y0 = ty * 32;
    const int tid = threadIdx.x;

    // ---- rotated weights -> ldsw[t][tap][o] bf16 (tap>=25 => 0) ----
    for (int e = tid; e < 1792; e += 256) {
        int t   = e / 224;
        int rem = e - t * 224;
        int tap = rem >> 3;
        int o   = rem & 7;
        float w = 0.0f;
        if (tap < 25) {
            int dy = tap / 5, dx = tap - 5 * (tap / 5);
            float ca = CA8[t], sa = SA8[t];
            float xx = (float)dx - 2.0f, yy = (float)dy - 2.0f;
            int iy = (int)rintf(sa * xx + ca * yy + 2.0f);  // RNE == jnp.round
            int ix = (int)rintf(ca * xx - sa * yy + 2.0f);
            if (iy >= 0 && iy < 5 && ix >= 0 && ix < 5) {
                int tp = (o - t) & 7;
                w = kern[(c * 8 + tp) * 25 + iy * 5 + ix];
            }
        }
        ldsw[e] = f2bf(w);
    }
    __syncthreads();   // ldsw producer -> wfrag consumer

    const float* xbase = x + (size_t)bc * 131072;

    auto loadch = [&](int e, float (&v)[8]) {
        int r = e / 36, col = e - r * 36;
        int gy = Y0 - 2 + r, gx = X0 - 2 + col;
        if (gy >= 0 && gy < 128 && gx >= 0 && gx < 128) {
            const float* src = xbase + gy * 128 + gx;
#pragma unroll
            for (int o = 0; o < 8; ++o) v[o] = src[o * 16384];
        } else {
#pragma unroll
            for (int o = 0; o < 8; ++o) v[o] = 0.0f;
        }
    };
    auto packch = [&](int e, const float (&v)[8]) {
        *reinterpret_cast<uint4*>(&ldsx[e * 8]) =
            make_uint4(pk2(v[0], v[1]), pk2(v[2], v[3]),
                       pk2(v[4], v[5]), pk2(v[6], v[7]));
    };

    const int lane  = tid & 63;
    const int wv    = tid >> 6;        // wave: rows y = wv*8 .. wv*8+7
    const int g     = lane >> 4;       // k-group
    const int col16 = lane & 15;

    float sA[8], sB[8];

    // round 1 loads issued first: their latency hides the wfrag ds_reads
    loadch(tid, sA);
    loadch(tid + 256, sB);

    bf16x8 wfrag[7];
    int    tapoff[7];
    const bf16x8 zfrag = {0, 0, 0, 0, 0, 0, 0, 0};
#pragma unroll
    for (int cc = 0; cc < 7; ++cc) {
        int tap  = cc * 4 + g;
        int tapc = tap < 25 ? tap : 24;
        int dy = tapc / 5, dx = tapc - 5 * (tapc / 5);
        tapoff[cc] = (dy * 36 + dx) * 8;          // in shorts
        wfrag[cc] = (col16 < 8)
            ? *reinterpret_cast<const bf16x8*>(&ldsw[(col16 * 28 + tap) * 8])
            : zfrag;
    }

    packch(tid, sA);
    packch(tid + 256, sB);
    loadch(tid + 512, sA);
    loadch(tid + 768, sB);
    packch(tid + 512, sA);
    packch(tid + 768, sB);
    loadch(tid + 1024, sA);
    if (tid < 16) loadch(tid + 1280, sB);
    packch(tid + 1024, sA);
    if (tid < 16) packch(tid + 1280, sB);
    __syncthreads();

    float* outl = out + (size_t)bc * 131072 + (size_t)col16 * 16384 +
                  (size_t)Y0 * 128 + X0 + g * 4;

    // ---- compute: 8 row-pairs per wave, 2 xh per pair, unroll 2 ----
#pragma unroll 2
    for (int cp = 0; cp < 8; ++cp) {
        int y = wv * 8 + cp;
        int baseS = (y * 36 + col16) * 8;
        f32x4 acc0 = {0.f, 0.f, 0.f, 0.f};
        f32x4 acc1 = {0.f, 0.f, 0.f, 0.f};
#pragma unroll
        for (int cc = 0; cc < 7; ++cc) {
            bf16x8 xf0 = *reinterpret_cast<const bf16x8*>(&ldsx[baseS + tapoff[cc]]);
            bf16x8 xf1 = *reinterpret_cast<const bf16x8*>(&ldsx[baseS + 128 + tapoff[cc]]);
            acc0 = __builtin_amdgcn_mfma_f32_16x16x32_bf16(xf0, wfrag[cc], acc0, 0, 0, 0);
            acc1 = __builtin_amdgcn_mfma_f32_16x16x32_bf16(xf1, wfrag[cc], acc1, 0, 0, 0);
        }
        if (col16 < 8) {
            float* po = outl + (size_t)y * 128;
            *reinterpret_cast<float4*>(po)      = make_float4(acc0[0], acc0[1], acc0[2], acc0[3]);
            *reinterpret_cast<float4*>(po + 16) = make_float4(acc1[0], acc1[1], acc1[2], acc1[3]);
        }
    }
}

extern "C" void kernel_launch(void* const* d_in, const int* in_sizes, int n_in,
                              void* d_out, int out_size, void* d_ws, size_t ws_size,
                              hipStream_t stream) {
    const float* x    = (const float*)d_in[0];
    const float* kern = (const float*)d_in[1];
    float* out = (float*)d_out;
    dim3 grid(4096), block(256);   // 8b * 32c * 4ty * 4tx (swizzled in-kernel)
    se2_mfma<<<grid, block, 0, stream>>>(x, kern, out);
}